// Round 1
// baseline (972.101 us; speedup 1.0000x reference)
//
#include <hip/hip_runtime.h>

#define H 128
#define LBL 8

// ---------------- CSR build ----------------

__global__ void hist_csr(const int* __restrict__ dst, int E, int* __restrict__ cnt) {
    int i = blockIdx.x * blockDim.x + threadIdx.x;
    int stride = gridDim.x * blockDim.x;
    for (; i < E; i += stride) atomicAdd(&cnt[dst[i]], 1);
}

// one block per message type; exclusive scan of cnt[n] -> offs[n+1]
__global__ void scan3(const int* __restrict__ cnt, int* __restrict__ offs, int n) {
    __shared__ int buf[1024];
    __shared__ int carry;
    const int* c = cnt + (size_t)blockIdx.x * n;
    int* o = offs + (size_t)blockIdx.x * (n + 1);
    if (threadIdx.x == 0) carry = 0;
    __syncthreads();
    for (int base = 0; base < n; base += 1024) {
        int i = base + threadIdx.x;
        int v = (i < n) ? c[i] : 0;
        buf[threadIdx.x] = v;
        __syncthreads();
        #pragma unroll
        for (int off = 1; off < 1024; off <<= 1) {
            int t = (threadIdx.x >= off) ? buf[threadIdx.x - off] : 0;
            __syncthreads();
            buf[threadIdx.x] += t;
            __syncthreads();
        }
        if (i < n) o[i] = carry + buf[threadIdx.x] - v;
        __syncthreads();
        if (threadIdx.x == 1023) carry += buf[1023];
        __syncthreads();
    }
    if (threadIdx.x == 0) o[n] = carry;
}

__global__ void cur_init(const int* __restrict__ offs, int* __restrict__ cur, int n) {
    int i = blockIdx.x * blockDim.x + threadIdx.x;
    if (i >= 3 * n) return;
    int m = i / n, j = i - m * n;
    cur[i] = offs[(size_t)m * (n + 1) + j];
}

__global__ void fill_csr(const int* __restrict__ src, const int* __restrict__ dst, int E,
                         int* __restrict__ cur, int* __restrict__ srcs) {
    int i = blockIdx.x * blockDim.x + threadIdx.x;
    int stride = gridDim.x * blockDim.x;
    for (; i < E; i += stride) {
        int d = dst[i];
        int p = atomicAdd(&cur[d], 1);
        srcs[p] = src[i];
    }
}

// ---------------- segment mean (CSR) ----------------
// one wave per dst row; lane holds 2 channels (float2)
__global__ void agg_mean(const float* __restrict__ xsrc, const int* __restrict__ offs,
                         const int* __restrict__ srcs, float* __restrict__ out, int n) {
    int row = blockIdx.x * 4 + (threadIdx.x >> 6);
    int lane = threadIdx.x & 63;
    if (row >= n) return;
    int s = offs[row], e = offs[row + 1];
    float ax = 0.f, ay = 0.f;
    int i = s;
    for (; i + 1 < e; i += 2) {
        int s0 = srcs[i], s1 = srcs[i + 1];
        float2 v0 = ((const float2*)xsrc)[(size_t)s0 * 64 + lane];
        float2 v1 = ((const float2*)xsrc)[(size_t)s1 * 64 + lane];
        ax += v0.x + v1.x;
        ay += v0.y + v1.y;
    }
    if (i < e) {
        int s0 = srcs[i];
        float2 v0 = ((const float2*)xsrc)[(size_t)s0 * 64 + lane];
        ax += v0.x;
        ay += v0.y;
    }
    int d = e - s;
    float inv = 1.f / (float)(d > 0 ? d : 1);
    ((float2*)out)[(size_t)row * 64 + lane] = make_float2(ax * inv, ay * inv);
}

// ---------------- small weight-fusion GEMMs (128x128x128) ----------------
__global__ void fuse_w(float* __restrict__ C, const float* __restrict__ A,
                       const float* __restrict__ B, float alpha, int betaNZ) {
    int i = blockIdx.x;
    int j = threadIdx.x;
    float s = 0.f;
    for (int k = 0; k < 128; ++k) s += A[i * 128 + k] * B[k * 128 + j];
    float r = alpha * s;
    if (betaNZ) r += C[i * 128 + j];
    C[i * 128 + j] = r;
}

__global__ void fuse_bias(float* __restrict__ fc, const float* __restrict__ bn,
                          const float* __restrict__ bs, const float* __restrict__ bu,
                          const float* __restrict__ Wu /*256x128*/, float alpha, int betaNZ) {
    int j = threadIdx.x;
    float s = bu[j];
    for (int k = 0; k < 128; ++k)
        s += bn[k] * Wu[k * 128 + j] + bs[k] * Wu[(128 + k) * 128 + j];
    float r = alpha * s;
    if (betaNZ) r += fc[j];
    fc[j] = r;
}

// ---------------- main GEMM: C[M,128] = sum_i A_i[M,128] @ W_i[128,128] + bias ----------------
// also accumulates per-column sum / sumsq for BN (rows < M only)
__global__ __launch_bounds__(256) void gemm_multi(
    const float* __restrict__ A0, const float* __restrict__ W0,
    const float* __restrict__ A1, const float* __restrict__ W1,
    const float* __restrict__ A2, const float* __restrict__ W2,
    int nIn, const float* __restrict__ bias, float* __restrict__ C, int M,
    float* __restrict__ colsum, float* __restrict__ colsq) {
    __shared__ float As[64][36];
    __shared__ float Wsh[32 * 128];
    int tid = threadIdx.x;
    int cg = tid & 31;   // cols cg, cg+32, cg+64, cg+96
    int rg = tid >> 5;   // rows rg*8 .. rg*8+7
    int row0 = blockIdx.x * 64;
    float acc[8][4];
    #pragma unroll
    for (int i = 0; i < 8; ++i)
        #pragma unroll
        for (int j = 0; j < 4; ++j) acc[i][j] = 0.f;

    for (int inp = 0; inp < nIn; ++inp) {
        const float* A = (inp == 0) ? A0 : ((inp == 1) ? A1 : A2);
        const float* W = (inp == 0) ? W0 : ((inp == 1) ? W1 : W2);
        for (int k0 = 0; k0 < 128; k0 += 32) {
            {   // stage A chunk 64x32
                int r = tid >> 2;
                int kq = (tid & 3) * 8;
                int gr = row0 + r;
                float4 v0 = make_float4(0, 0, 0, 0), v1 = v0;
                if (gr < M) {
                    const float* srcp = A + (size_t)gr * 128 + k0 + kq;
                    v0 = *(const float4*)srcp;
                    v1 = *(const float4*)(srcp + 4);
                }
                *(float4*)&As[r][kq] = v0;
                *(float4*)&As[r][kq + 4] = v1;
            }
            {   // stage W chunk 32x128 (contiguous)
                const float4* src4 = (const float4*)(W + (size_t)k0 * 128);
                float4* dst4 = (float4*)Wsh;
                #pragma unroll
                for (int j = 0; j < 4; ++j) dst4[tid + 256 * j] = src4[tid + 256 * j];
            }
            __syncthreads();
            #pragma unroll 2
            for (int kk4 = 0; kk4 < 32; kk4 += 4) {
                float4 a4[8];
                #pragma unroll
                for (int i = 0; i < 8; ++i) a4[i] = *(const float4*)&As[rg * 8 + i][kk4];
                #pragma unroll
                for (int u = 0; u < 4; ++u) {
                    int kk = kk4 + u;
                    float w0 = Wsh[kk * 128 + cg];
                    float w1 = Wsh[kk * 128 + cg + 32];
                    float w2 = Wsh[kk * 128 + cg + 64];
                    float w3 = Wsh[kk * 128 + cg + 96];
                    #pragma unroll
                    for (int i = 0; i < 8; ++i) {
                        float a = (u == 0) ? a4[i].x : ((u == 1) ? a4[i].y : ((u == 2) ? a4[i].z : a4[i].w));
                        acc[i][0] += a * w0;
                        acc[i][1] += a * w1;
                        acc[i][2] += a * w2;
                        acc[i][3] += a * w3;
                    }
                }
            }
            __syncthreads();
        }
    }

    float b0 = bias[cg], b1 = bias[cg + 32], b2 = bias[cg + 64], b3 = bias[cg + 96];
    float ps[4] = {0, 0, 0, 0}, pq[4] = {0, 0, 0, 0};
    #pragma unroll
    for (int i = 0; i < 8; ++i) {
        int r = row0 + rg * 8 + i;
        if (r < M) {
            float o0 = acc[i][0] + b0, o1 = acc[i][1] + b1, o2 = acc[i][2] + b2, o3 = acc[i][3] + b3;
            float* crow = C + (size_t)r * 128;
            crow[cg] = o0; crow[cg + 32] = o1; crow[cg + 64] = o2; crow[cg + 96] = o3;
            ps[0] += o0; ps[1] += o1; ps[2] += o2; ps[3] += o3;
            pq[0] += o0 * o0; pq[1] += o1 * o1; pq[2] += o2 * o2; pq[3] += o3 * o3;
        }
    }
    // block-reduce column partials, then one atomic per column
    #pragma unroll
    for (int j = 0; j < 4; ++j) Wsh[rg * 128 + cg + 32 * j] = ps[j];
    __syncthreads();
    if (tid < 128) {
        float s = 0.f;
        #pragma unroll
        for (int g = 0; g < 8; ++g) s += Wsh[g * 128 + tid];
        atomicAdd(&colsum[tid], s);
    }
    __syncthreads();
    #pragma unroll
    for (int j = 0; j < 4; ++j) Wsh[rg * 128 + cg + 32 * j] = pq[j];
    __syncthreads();
    if (tid < 128) {
        float q = 0.f;
        #pragma unroll
        for (int g = 0; g < 8; ++g) q += Wsh[g * 128 + tid];
        atomicAdd(&colsq[tid], q);
    }
}

// ---------------- BN finalize + apply ----------------
__global__ void bn_fin(const float* __restrict__ colsum, const float* __restrict__ colsq,
                       const float* __restrict__ gamma, const float* __restrict__ beta,
                       float* __restrict__ scale, float* __restrict__ shift, int N) {
    int c = threadIdx.x;
    float m = colsum[c] / (float)N;
    float v = colsq[c] / (float)N - m * m;
    float rs = rsqrtf(v + 1e-5f);
    float sc = gamma[c] * rs;
    scale[c] = sc;
    shift[c] = beta[c] - m * sc;
}

__global__ void bn_apply(const float* __restrict__ in, float* __restrict__ out,
                         const float* __restrict__ scale, const float* __restrict__ shift, int n4) {
    int i = blockIdx.x * blockDim.x + threadIdx.x;
    int stride = gridDim.x * blockDim.x;
    for (; i < n4; i += stride) {
        float4 v = ((const float4*)in)[i];
        int cb = (i * 4) & 127;
        float4 sc = *(const float4*)&scale[cb];
        float4 sh = *(const float4*)&shift[cb];
        float y0 = v.x * sc.x + sh.x;
        float y1 = v.y * sc.y + sh.y;
        float y2 = v.z * sc.z + sh.z;
        float y3 = v.w * sc.w + sh.w;
        y0 = (y0 >= 0.f) ? y0 : 0.01f * y0;
        y1 = (y1 >= 0.f) ? y1 : 0.01f * y1;
        y2 = (y2 >= 0.f) ? y2 : 0.01f * y2;
        y3 = (y3 >= 0.f) ? y3 : 0.01f * y3;
        ((float4*)out)[i] = make_float4(y0, y1, y2, y3);
    }
}

// ---------------- final projection [N,128] @ [128,8] + b ----------------
__global__ void proj(const float* __restrict__ h, const float* __restrict__ Wp,
                     const float* __restrict__ bp, float* __restrict__ out, int N) {
    int idx = blockIdx.x * blockDim.x + threadIdx.x;
    if (idx >= N * LBL) return;
    int r = idx >> 3, c = idx & 7;
    const float* hr = h + (size_t)r * 128;
    float s = bp[c];
    #pragma unroll 4
    for (int k = 0; k < 128; ++k) s += hr[k] * Wp[k * LBL + c];
    out[idx] = s;
}

// ---------------- host ----------------

extern "C" void kernel_launch(void* const* d_in, const int* in_sizes, int n_in,
                              void* d_out, int out_size, void* d_ws, size_t ws_size,
                              hipStream_t stream) {
    const float* x0 = (const float*)d_in[0];
    const float* x1 = (const float*)d_in[1];
    const float* Wn[2] = {(const float*)d_in[2], (const float*)d_in[5]};
    const float* Ws[2] = {(const float*)d_in[3], (const float*)d_in[6]};
    const float* Wu[2] = {(const float*)d_in[4], (const float*)d_in[7]};
    const float* bnn[2] = {(const float*)d_in[8], (const float*)d_in[11]};
    const float* bss[2] = {(const float*)d_in[9], (const float*)d_in[12]};
    const float* buu[2] = {(const float*)d_in[10], (const float*)d_in[13]};
    const float* gam[2] = {(const float*)d_in[14], (const float*)d_in[16]};
    const float* bet[2] = {(const float*)d_in[15], (const float*)d_in[17]};
    const float* Wp = (const float*)d_in[18];
    const float* bp = (const float*)d_in[19];
    const int* ei[3] = {(const int*)d_in[20], (const int*)d_in[21], (const int*)d_in[22]};

    const int N = in_sizes[0] / 128;
    const int E = in_sizes[20] / 2;
    float* out = (float*)d_out;

    // ---- workspace carve ----
    char* wp_ = (char*)d_ws;
    auto carve = [&](size_t bytes) {
        char* r = wp_;
        wp_ += (bytes + 255) & ~(size_t)255;
        return r;
    };
    size_t nodeBytes = (size_t)N * 128 * sizeof(float);
    float* P  = (float*)carve(nodeBytes);  // agg0 / h0pre
    float* Q  = (float*)carve(nodeBytes);  // h1pre
    float* R  = (float*)carve(nodeBytes);  // agg1
    float* S  = (float*)carve(nodeBytes);  // agg2
    float* X0 = (float*)carve(nodeBytes);  // activated n0
    float* X1 = (float*)carve(nodeBytes);  // activated n1
    float* FA0 = (float*)carve(16384 * 4);
    float* FA1 = (float*)carve(16384 * 4);
    float* FA2 = (float*)carve(16384 * 4);
    float* FB1 = (float*)carve(16384 * 4);
    float* FB0 = (float*)carve(16384 * 4);
    float* fcH0 = (float*)carve(128 * 4);
    float* fcH1 = (float*)carve(128 * 4);
    float* ST = (float*)carve(1024 * 4);  // colsum0,colsq0,colsum1,colsq1,sc0,sh0,sc1,sh1
    int* cnt  = (int*)carve((size_t)3 * N * 4);
    int* offs = (int*)carve((size_t)3 * (N + 1) * 4);
    int* cur  = (int*)carve((size_t)3 * N * 4);
    int* srcs = (int*)carve((size_t)3 * E * 4);

    float* SC0 = ST + 512; float* SH0 = ST + 640;
    float* SC1 = ST + 768; float* SH1 = ST + 896;

    const int eg = (E + 255) / 256;           // edge-parallel grid
    const int ag = (N + 3) / 4;               // agg grid (wave per row)
    const int gg = (N + 63) / 64;             // gemm grid
    const int pg = (N * LBL + 255) / 256;     // proj grid

    // ---- CSR build (shared by both layers) ----
    hipMemsetAsync(cnt, 0, (size_t)3 * N * 4, stream);
    hist_csr<<<eg, 256, 0, stream>>>(ei[0] + E, E, cnt);
    hist_csr<<<eg, 256, 0, stream>>>(ei[1] + E, E, cnt + N);
    hist_csr<<<eg, 256, 0, stream>>>(ei[2] + E, E, cnt + 2 * N);
    scan3<<<3, 1024, 0, stream>>>(cnt, offs, N);
    cur_init<<<(3 * N + 255) / 256, 256, 0, stream>>>(offs, cur, N);
    fill_csr<<<eg, 256, 0, stream>>>(ei[0], ei[0] + E, E, cur, srcs);
    fill_csr<<<eg, 256, 0, stream>>>(ei[1], ei[1] + E, E, cur + N, srcs + E);
    fill_csr<<<eg, 256, 0, stream>>>(ei[2], ei[2] + E, E, cur + 2 * N, srcs + 2 * E);

    const float* srcA[2][3] = {{x0, x1, x0}, {X0, X1, X0}};  // per-layer gather sources
    const float* dstX[2][2];  // per-layer x_dst inputs: [layer][node type]
    dstX[0][0] = x0; dstX[0][1] = x1;
    dstX[1][0] = X0; dstX[1][1] = X1;

    for (int l = 0; l < 2; ++l) {
        // ---- fuse weights: FA_t = Wn[t] @ Wu[t]_top ; FB = Ws @ Wu_bot ; biases ----
        fuse_w<<<128, 128, 0, stream>>>(FA0, Wn[l],         Wu[l],                 1.0f, 0);
        fuse_w<<<128, 128, 0, stream>>>(FA1, Wn[l] + 16384, Wu[l] + 32768,         0.5f, 0);
        fuse_w<<<128, 128, 0, stream>>>(FA2, Wn[l] + 32768, Wu[l] + 65536,         0.5f, 0);
        fuse_w<<<128, 128, 0, stream>>>(FB1, Ws[l],         Wu[l] + 16384,         1.0f, 0);
        fuse_w<<<128, 128, 0, stream>>>(FB0, Ws[l] + 16384, Wu[l] + 32768 + 16384, 0.5f, 0);
        fuse_w<<<128, 128, 0, stream>>>(FB0, Ws[l] + 32768, Wu[l] + 65536 + 16384, 0.5f, 1);
        fuse_bias<<<1, 128, 0, stream>>>(fcH1, bnn[l],       bss[l],       buu[l],       Wu[l],         1.0f, 0);
        fuse_bias<<<1, 128, 0, stream>>>(fcH0, bnn[l] + 128, bss[l] + 128, buu[l] + 128, Wu[l] + 32768, 0.5f, 0);
        fuse_bias<<<1, 128, 0, stream>>>(fcH0, bnn[l] + 256, bss[l] + 256, buu[l] + 256, Wu[l] + 65536, 0.5f, 1);

        // ---- aggregations ----
        agg_mean<<<ag, 256, 0, stream>>>(srcA[l][0], offs,               srcs,         P, N); // msg0 -> n1
        agg_mean<<<ag, 256, 0, stream>>>(srcA[l][1], offs + (N + 1),     srcs + E,     R, N); // msg1 -> n0
        agg_mean<<<ag, 256, 0, stream>>>(srcA[l][2], offs + 2 * (N + 1), srcs + 2 * E, S, N); // msg2 -> n0

        // ---- GEMMs with BN-stat epilogue ----
        hipMemsetAsync(ST, 0, 512 * 4, stream);
        gemm_multi<<<gg, 256, 0, stream>>>(P, FA0, dstX[l][1], FB1, P, FA0, 2, fcH1, Q, N,
                                           ST + 256, ST + 384);          // h1pre
        gemm_multi<<<gg, 256, 0, stream>>>(R, FA1, S, FA2, dstX[l][0], FB0, 3, fcH0, P, N,
                                           ST, ST + 128);                // h0pre (overwrites agg0)

        // ---- BN finalize + apply (+LeakyReLU) ----
        bn_fin<<<1, 128, 0, stream>>>(ST,       ST + 128, gam[l],       bet[l],       SC0, SH0, N);
        bn_fin<<<1, 128, 0, stream>>>(ST + 256, ST + 384, gam[l] + 128, bet[l] + 128, SC1, SH1, N);
        bn_apply<<<2048, 256, 0, stream>>>(P, X0, SC0, SH0, N * 32);
        bn_apply<<<2048, 256, 0, stream>>>(Q, X1, SC1, SH1, N * 32);
    }

    // ---- final projection ----
    proj<<<pg, 256, 0, stream>>>(X0, Wp,        bp,     out,                 N);
    proj<<<pg, 256, 0, stream>>>(X1, Wp + 1024, bp + 8, out + (size_t)N * 8, N);
}

// Round 2
// 780.877 us; speedup vs baseline: 1.2449x; 1.2449x over previous
//
#include <hip/hip_runtime.h>

#define LBL 8

typedef __attribute__((ext_vector_type(8))) short short8;
typedef __attribute__((ext_vector_type(4))) float f32x4;

__device__ __forceinline__ uint f2bf(float x) {
    uint u = __float_as_uint(x);
    return (u + 0x7fffu + ((u >> 16) & 1u)) >> 16;
}
__device__ __forceinline__ float bflo(uint v) { return __uint_as_float(v << 16); }
__device__ __forceinline__ float bfhi(uint v) { return __uint_as_float(v & 0xffff0000u); }

// ---------------- fp32 -> bf16 conversion ----------------
__global__ void f2b(const float4* __restrict__ in, uint2* __restrict__ out, int n4) {
    int i = blockIdx.x * blockDim.x + threadIdx.x;
    int stride = gridDim.x * blockDim.x;
    for (; i < n4; i += stride) {
        float4 v = in[i];
        uint2 o;
        o.x = f2bf(v.x) | (f2bf(v.y) << 16);
        o.y = f2bf(v.z) | (f2bf(v.w) << 16);
        out[i] = o;
    }
}

// ---------------- CSR build (3 message types batched via blockIdx.y) ----------------
__global__ void hist3(const int* __restrict__ e0, const int* __restrict__ e1,
                      const int* __restrict__ e2, int E, int* __restrict__ cnt, int N) {
    int m = blockIdx.y;
    const int* dst = (m == 0 ? e0 : (m == 1 ? e1 : e2)) + E;
    int* c = cnt + (size_t)m * N;
    int i = blockIdx.x * blockDim.x + threadIdx.x;
    int stride = gridDim.x * blockDim.x;
    for (; i < E; i += stride) atomicAdd(&c[dst[i]], 1);
}

__global__ void scan3(const int* __restrict__ cnt, int* __restrict__ offs, int n) {
    __shared__ int buf[1024];
    __shared__ int carry;
    const int* c = cnt + (size_t)blockIdx.x * n;
    int* o = offs + (size_t)blockIdx.x * (n + 1);
    if (threadIdx.x == 0) carry = 0;
    __syncthreads();
    for (int base = 0; base < n; base += 1024) {
        int i = base + threadIdx.x;
        int v = (i < n) ? c[i] : 0;
        buf[threadIdx.x] = v;
        __syncthreads();
        #pragma unroll
        for (int off = 1; off < 1024; off <<= 1) {
            int t = (threadIdx.x >= off) ? buf[threadIdx.x - off] : 0;
            __syncthreads();
            buf[threadIdx.x] += t;
            __syncthreads();
        }
        if (i < n) o[i] = carry + buf[threadIdx.x] - v;
        __syncthreads();
        if (threadIdx.x == 1023) carry += buf[1023];
        __syncthreads();
    }
    if (threadIdx.x == 0) o[n] = carry;
}

__global__ void cur_init(const int* __restrict__ offs, int* __restrict__ cur, int n) {
    int i = blockIdx.x * blockDim.x + threadIdx.x;
    if (i >= 3 * n) return;
    int m = i / n, j = i - m * n;
    cur[i] = offs[(size_t)m * (n + 1) + j];
}

__global__ void fill3(const int* __restrict__ e0, const int* __restrict__ e1,
                      const int* __restrict__ e2, int E, int N,
                      int* __restrict__ cur, int* __restrict__ srcs) {
    int m = blockIdx.y;
    const int* base = (m == 0 ? e0 : (m == 1 ? e1 : e2));
    const int* src = base;
    const int* dst = base + E;
    int* cu = cur + (size_t)m * N;
    int* sr = srcs + (size_t)m * E;
    int i = blockIdx.x * blockDim.x + threadIdx.x;
    int stride = gridDim.x * blockDim.x;
    for (; i < E; i += stride) {
        int d = dst[i];
        int p = atomicAdd(&cu[d], 1);
        sr[p] = src[i];
    }
}

// ---------------- segment mean (CSR, bf16 in / bf16 out), 3 types batched ----------------
__global__ void agg3(const ushort* __restrict__ s0, const ushort* __restrict__ s1,
                     const ushort* __restrict__ s2,
                     uint* __restrict__ o0, uint* __restrict__ o1, uint* __restrict__ o2,
                     const int* __restrict__ offs, const int* __restrict__ srcs,
                     int n, int E) {
    int m = blockIdx.y;
    const uint* x = (const uint*)(m == 0 ? s0 : (m == 1 ? s1 : s2));
    uint* o = (m == 0 ? o0 : (m == 1 ? o1 : o2));
    const int* off = offs + (size_t)m * (n + 1);
    const int* sl = srcs + (size_t)m * E;

    int row = blockIdx.x * 4 + (threadIdx.x >> 6);
    int lane = threadIdx.x & 63;
    if (row >= n) return;
    int s = off[row], e = off[row + 1];
    float ax = 0.f, ay = 0.f;
    int i = s;
    for (; i + 1 < e; i += 2) {
        uint v0 = x[(size_t)sl[i] * 64 + lane];
        uint v1 = x[(size_t)sl[i + 1] * 64 + lane];
        ax += bflo(v0) + bflo(v1);
        ay += bfhi(v0) + bfhi(v1);
    }
    if (i < e) {
        uint v0 = x[(size_t)sl[i] * 64 + lane];
        ax += bflo(v0);
        ay += bfhi(v0);
    }
    int d = e - s;
    float inv = 1.f / (float)(d > 0 ? d : 1);
    o[(size_t)row * 64 + lane] = f2bf(ax * inv) | (f2bf(ay * inv) << 16);
}

// ---------------- weight fusion: C = alpha*A@B (+C) ; also emit bf16 C^T ----------------
__global__ void fuse_w(float* __restrict__ C, ushort* __restrict__ CT,
                       const float* __restrict__ A, const float* __restrict__ B,
                       float alpha, int betaNZ) {
    int i = blockIdx.x;
    int j = threadIdx.x;
    float s = 0.f;
    for (int k = 0; k < 128; ++k) s += A[i * 128 + k] * B[k * 128 + j];
    float r = alpha * s;
    if (betaNZ) r += C[i * 128 + j];
    C[i * 128 + j] = r;
    CT[j * 128 + i] = (ushort)f2bf(r);   // transposed bf16 for MFMA B-fragments
}

__global__ void fuse_bias(float* __restrict__ fc, const float* __restrict__ bn,
                          const float* __restrict__ bs, const float* __restrict__ bu,
                          const float* __restrict__ Wu /*256x128*/, float alpha, int betaNZ) {
    int j = threadIdx.x;
    float s = bu[j];
    for (int k = 0; k < 128; ++k)
        s += bn[k] * Wu[k * 128 + j] + bs[k] * Wu[(128 + k) * 128 + j];
    float r = alpha * s;
    if (betaNZ) r += fc[j];
    fc[j] = r;
}

// ---------------- MFMA GEMM: C[M,128] = sum_i A_i[M,128]@W_i + bias, + BN col stats ----------------
// A_i bf16 row-major [M][128]; W_i bf16 TRANSPOSED [n][k] (128x128). C fp32.
#define APITCH 136
__global__ __launch_bounds__(256) void gemm_mfma(
    const ushort* __restrict__ A0, const ushort* __restrict__ W0,
    const ushort* __restrict__ A1, const ushort* __restrict__ W1,
    const ushort* __restrict__ A2, const ushort* __restrict__ W2,
    int nIn, const float* __restrict__ bias, float* __restrict__ C, int M,
    float* __restrict__ colsum, float* __restrict__ colsq) {
    __shared__ ushort As[64 * APITCH];
    int tid = threadIdx.x;
    int wid = tid >> 6;        // wave -> cols wid*32 .. wid*32+31
    int lane = tid & 63;
    int l15 = lane & 15, lg = lane >> 4;
    int row0 = blockIdx.x * 64;

    f32x4 acc[4][2];
    #pragma unroll
    for (int rb = 0; rb < 4; ++rb)
        #pragma unroll
        for (int cb = 0; cb < 2; ++cb) acc[rb][cb] = (f32x4){0.f, 0.f, 0.f, 0.f};

    for (int inp = 0; inp < nIn; ++inp) {
        const ushort* A = (inp == 0) ? A0 : ((inp == 1) ? A1 : A2);
        const ushort* W = (inp == 0) ? W0 : ((inp == 1) ? W1 : W2);
        __syncthreads();
        {   // stage A tile 64x128 bf16 -> LDS (padded pitch)
            int r = tid >> 4;
            int c8 = (tid & 15) * 8;
            #pragma unroll
            for (int p = 0; p < 4; ++p) {
                int rr = p * 16 + r;
                int gr = row0 + rr;
                uint4 v = make_uint4(0, 0, 0, 0);
                if (gr < M) v = *(const uint4*)(A + (size_t)gr * 128 + c8);
                *(uint4*)(&As[rr * APITCH + c8]) = v;
            }
        }
        __syncthreads();
        #pragma unroll
        for (int k0 = 0; k0 < 128; k0 += 32) {
            int ka = k0 + lg * 8;
            short8 a[4], b[2];
            #pragma unroll
            for (int rb = 0; rb < 4; ++rb)
                a[rb] = *(const short8*)(&As[(rb * 16 + l15) * APITCH + ka]);
            #pragma unroll
            for (int cb = 0; cb < 2; ++cb) {
                int col = wid * 32 + cb * 16 + l15;
                b[cb] = *(const short8*)(W + (size_t)col * 128 + ka);
            }
            #pragma unroll
            for (int rb = 0; rb < 4; ++rb)
                #pragma unroll
                for (int cb = 0; cb < 2; ++cb)
                    acc[rb][cb] = __builtin_amdgcn_mfma_f32_16x16x32_bf16(a[rb], b[cb], acc[rb][cb], 0, 0, 0);
        }
    }

    // epilogue: bias add, C store, BN column partials
    float ps[2] = {0.f, 0.f}, pq[2] = {0.f, 0.f};
    int colbase = wid * 32;
    #pragma unroll
    for (int cb = 0; cb < 2; ++cb) {
        int col = colbase + cb * 16 + l15;
        float b = bias[col];
        #pragma unroll
        for (int rb = 0; rb < 4; ++rb) {
            int rbase = row0 + rb * 16 + lg * 4;
            #pragma unroll
            for (int i = 0; i < 4; ++i) {
                int r = rbase + i;
                if (r < M) {
                    float v = acc[rb][cb][i] + b;
                    C[(size_t)r * 128 + col] = v;
                    ps[cb] += v;
                    pq[cb] += v * v;
                }
            }
        }
    }
    #pragma unroll
    for (int cb = 0; cb < 2; ++cb) {
        ps[cb] += __shfl_xor(ps[cb], 16, 64);
        ps[cb] += __shfl_xor(ps[cb], 32, 64);
        pq[cb] += __shfl_xor(pq[cb], 16, 64);
        pq[cb] += __shfl_xor(pq[cb], 32, 64);
    }
    if (lane < 16) {
        atomicAdd(&colsum[colbase + lane], ps[0]);
        atomicAdd(&colsq[colbase + lane], pq[0]);
        atomicAdd(&colsum[colbase + 16 + lane], ps[1]);
        atomicAdd(&colsq[colbase + 16 + lane], pq[1]);
    }
}

// ---------------- BN finalize + apply ----------------
__global__ void bn_fin(const float* __restrict__ colsum, const float* __restrict__ colsq,
                       const float* __restrict__ gamma, const float* __restrict__ beta,
                       float* __restrict__ scale, float* __restrict__ shift, int N) {
    int c = threadIdx.x;
    float m = colsum[c] / (float)N;
    float v = colsq[c] / (float)N - m * m;
    float rs = rsqrtf(v + 1e-5f);
    float sc = gamma[c] * rs;
    scale[c] = sc;
    shift[c] = beta[c] - m * sc;
}

// fp32 in -> bf16 out, scale/shift + LeakyReLU
__global__ void bn_apply_b(const float4* __restrict__ in, uint2* __restrict__ out,
                           const float* __restrict__ scale, const float* __restrict__ shift, int n4) {
    int i = blockIdx.x * blockDim.x + threadIdx.x;
    int stride = gridDim.x * blockDim.x;
    for (; i < n4; i += stride) {
        float4 v = in[i];
        int cb = (i * 4) & 127;
        float4 sc = *(const float4*)&scale[cb];
        float4 sh = *(const float4*)&shift[cb];
        float y0 = v.x * sc.x + sh.x;
        float y1 = v.y * sc.y + sh.y;
        float y2 = v.z * sc.z + sh.z;
        float y3 = v.w * sc.w + sh.w;
        y0 = (y0 >= 0.f) ? y0 : 0.01f * y0;
        y1 = (y1 >= 0.f) ? y1 : 0.01f * y1;
        y2 = (y2 >= 0.f) ? y2 : 0.01f * y2;
        y3 = (y3 >= 0.f) ? y3 : 0.01f * y3;
        uint2 o;
        o.x = f2bf(y0) | (f2bf(y1) << 16);
        o.y = f2bf(y2) | (f2bf(y3) << 16);
        out[i] = o;
    }
}

// ---------------- final projection [N,128]bf16 @ [128,8] + b ----------------
__global__ void proj_b(const uint* __restrict__ h, const float* __restrict__ Wp,
                       const float* __restrict__ bp, float* __restrict__ out, int N) {
    __shared__ float Wsh[1024];
    __shared__ float bsh[8];
    int tid = threadIdx.x;
    for (int i = tid; i < 1024; i += 256) Wsh[i] = Wp[i];
    if (tid < 8) bsh[tid] = bp[tid];
    __syncthreads();
    int idx = blockIdx.x * 256 + tid;
    if (idx >= N * LBL) return;
    int r = idx >> 3, c = idx & 7;
    const uint* hr = h + (size_t)r * 64;
    float s = bsh[c];
    #pragma unroll
    for (int k2 = 0; k2 < 64; ++k2) {
        uint v = hr[k2];
        s += bflo(v) * Wsh[(2 * k2) * 8 + c] + bfhi(v) * Wsh[(2 * k2 + 1) * 8 + c];
    }
    out[idx] = s;
}

// ---------------- host ----------------

extern "C" void kernel_launch(void* const* d_in, const int* in_sizes, int n_in,
                              void* d_out, int out_size, void* d_ws, size_t ws_size,
                              hipStream_t stream) {
    const float* x0 = (const float*)d_in[0];
    const float* x1 = (const float*)d_in[1];
    const float* Wn[2] = {(const float*)d_in[2], (const float*)d_in[5]};
    const float* Ws[2] = {(const float*)d_in[3], (const float*)d_in[6]};
    const float* Wu[2] = {(const float*)d_in[4], (const float*)d_in[7]};
    const float* bnn[2] = {(const float*)d_in[8], (const float*)d_in[11]};
    const float* bss[2] = {(const float*)d_in[9], (const float*)d_in[12]};
    const float* buu[2] = {(const float*)d_in[10], (const float*)d_in[13]};
    const float* gam[2] = {(const float*)d_in[14], (const float*)d_in[16]};
    const float* bet[2] = {(const float*)d_in[15], (const float*)d_in[17]};
    const float* Wp = (const float*)d_in[18];
    const float* bp = (const float*)d_in[19];
    const int* ei[3] = {(const int*)d_in[20], (const int*)d_in[21], (const int*)d_in[22]};

    const int N = in_sizes[0] / 128;
    const int E = in_sizes[20] / 2;
    float* out = (float*)d_out;

    // ---- workspace carve ----
    char* wp_ = (char*)d_ws;
    auto carve = [&](size_t bytes) {
        char* r = wp_;
        wp_ += (bytes + 255) & ~(size_t)255;
        return r;
    };
    size_t nodeF = (size_t)N * 128 * sizeof(float);
    size_t nodeB = (size_t)N * 128 * sizeof(ushort);
    float* Cp = (float*)carve(nodeF);    // h0pre fp32
    float* Cq = (float*)carve(nodeF);    // h1pre fp32
    ushort* Pb = (ushort*)carve(nodeB);  // agg msg0 (dst n1)
    ushort* Rb = (ushort*)carve(nodeB);  // agg msg1 (dst n0)
    ushort* Sb = (ushort*)carve(nodeB);  // agg msg2 (dst n0)
    ushort* X0b = (ushort*)carve(nodeB); // activated n0 bf16
    ushort* X1b = (ushort*)carve(nodeB); // activated n1 bf16
    ushort* x0b = (ushort*)carve(nodeB); // input n0 bf16
    ushort* x1b = (ushort*)carve(nodeB); // input n1 bf16
    float* FA0 = (float*)carve(16384 * 4);
    float* FA1 = (float*)carve(16384 * 4);
    float* FA2 = (float*)carve(16384 * 4);
    float* FB1 = (float*)carve(16384 * 4);
    float* FB0 = (float*)carve(16384 * 4);
    ushort* FA0T = (ushort*)carve(16384 * 2);
    ushort* FA1T = (ushort*)carve(16384 * 2);
    ushort* FA2T = (ushort*)carve(16384 * 2);
    ushort* FB1T = (ushort*)carve(16384 * 2);
    ushort* FB0T = (ushort*)carve(16384 * 2);
    float* fcH0 = (float*)carve(128 * 4);
    float* fcH1 = (float*)carve(128 * 4);
    float* ST = (float*)carve(1024 * 4);
    int* cnt = (int*)carve((size_t)3 * N * 4);
    int* offs = (int*)carve((size_t)3 * (N + 1) * 4);
    int* cur = (int*)carve((size_t)3 * N * 4);
    int* srcs = (int*)carve((size_t)3 * E * 4);

    float* SC0 = ST + 512; float* SH0 = ST + 640;
    float* SC1 = ST + 768; float* SH1 = ST + 896;

    const int eg = (E + 255) / 256;
    const int ag = (N + 3) / 4;
    const int gg = (N + 63) / 64;
    const int pg = (N * LBL + 255) / 256;

    // ---- input bf16 conversion ----
    f2b<<<2048, 256, 0, stream>>>((const float4*)x0, (uint2*)x0b, N * 32);
    f2b<<<2048, 256, 0, stream>>>((const float4*)x1, (uint2*)x1b, N * 32);

    // ---- CSR build (shared by both layers) ----
    hipMemsetAsync(cnt, 0, (size_t)3 * N * 4, stream);
    hist3<<<dim3(eg, 3), 256, 0, stream>>>(ei[0], ei[1], ei[2], E, cnt, N);
    scan3<<<3, 1024, 0, stream>>>(cnt, offs, N);
    cur_init<<<(3 * N + 255) / 256, 256, 0, stream>>>(offs, cur, N);
    fill3<<<dim3(eg, 3), 256, 0, stream>>>(ei[0], ei[1], ei[2], E, N, cur, srcs);

    const ushort* srcS[2][3] = {{x0b, x1b, x0b}, {X0b, X1b, X0b}};
    const ushort* dstX[2][2] = {{x0b, x1b}, {X0b, X1b}};

    for (int l = 0; l < 2; ++l) {
        // ---- fuse weights into 5 effective 128x128 bf16 matrices (+transposed) ----
        fuse_w<<<128, 128, 0, stream>>>(FA0, FA0T, Wn[l],         Wu[l],                 1.0f, 0);
        fuse_w<<<128, 128, 0, stream>>>(FA1, FA1T, Wn[l] + 16384, Wu[l] + 32768,         0.5f, 0);
        fuse_w<<<128, 128, 0, stream>>>(FA2, FA2T, Wn[l] + 32768, Wu[l] + 65536,         0.5f, 0);
        fuse_w<<<128, 128, 0, stream>>>(FB1, FB1T, Ws[l],         Wu[l] + 16384,         1.0f, 0);
        fuse_w<<<128, 128, 0, stream>>>(FB0, FB0T, Ws[l] + 16384, Wu[l] + 32768 + 16384, 0.5f, 0);
        fuse_w<<<128, 128, 0, stream>>>(FB0, FB0T, Ws[l] + 32768, Wu[l] + 65536 + 16384, 0.5f, 1);
        fuse_bias<<<1, 128, 0, stream>>>(fcH1, bnn[l],       bss[l],       buu[l],       Wu[l],         1.0f, 0);
        fuse_bias<<<1, 128, 0, stream>>>(fcH0, bnn[l] + 128, bss[l] + 128, buu[l] + 128, Wu[l] + 32768, 0.5f, 0);
        fuse_bias<<<1, 128, 0, stream>>>(fcH0, bnn[l] + 256, bss[l] + 256, buu[l] + 256, Wu[l] + 65536, 0.5f, 1);

        // ---- aggregations (bf16 gather -> bf16 out), 3 types in one dispatch ----
        agg3<<<dim3(ag, 3), 256, 0, stream>>>(srcS[l][0], srcS[l][1], srcS[l][2],
                                              (uint*)Pb, (uint*)Rb, (uint*)Sb,
                                              offs, srcs, N, E);

        // ---- MFMA GEMMs with BN-stat epilogue ----
        hipMemsetAsync(ST, 0, 512 * 4, stream);
        gemm_mfma<<<gg, 256, 0, stream>>>(Pb, FA0T, dstX[l][1], FB1T, nullptr, nullptr,
                                          2, fcH1, Cq, N, ST + 256, ST + 384);   // h1pre
        gemm_mfma<<<gg, 256, 0, stream>>>(Rb, FA1T, Sb, FA2T, dstX[l][0], FB0T,
                                          3, fcH0, Cp, N, ST, ST + 128);         // h0pre

        // ---- BN finalize + apply (+LeakyReLU) -> bf16 ----
        bn_fin<<<1, 128, 0, stream>>>(ST,       ST + 128, gam[l],       bet[l],       SC0, SH0, N);
        bn_fin<<<1, 128, 0, stream>>>(ST + 256, ST + 384, gam[l] + 128, bet[l] + 128, SC1, SH1, N);
        bn_apply_b<<<2048, 256, 0, stream>>>((const float4*)Cp, (uint2*)X0b, SC0, SH0, N * 32);
        bn_apply_b<<<2048, 256, 0, stream>>>((const float4*)Cq, (uint2*)X1b, SC1, SH1, N * 32);
    }

    // ---- final projection ----
    proj_b<<<pg, 256, 0, stream>>>((const uint*)X0b, Wp,        bp,     out,                 N);
    proj_b<<<pg, 256, 0, stream>>>((const uint*)X1b, Wp + 1024, bp + 8, out + (size_t)N * 8, N);
}

// Round 3
// 446.739 us; speedup vs baseline: 2.1760x; 1.7479x over previous
//
#include <hip/hip_runtime.h>

#define LBL 8
#define NBMAX 128
#define BSH 9            // 512 dsts per bucket
#define BCAP 8192        // LDS sort capacity per bucket (mean ~5100, 43 sigma slack)

typedef __attribute__((ext_vector_type(8))) short short8;
typedef __attribute__((ext_vector_type(4))) float f32x4;

__device__ __forceinline__ uint f2bf(float x) {
    uint u = __float_as_uint(x);
    return (u + 0x7fffu + ((u >> 16) & 1u)) >> 16;
}
__device__ __forceinline__ float bflo(uint v) { return __uint_as_float(v << 16); }
__device__ __forceinline__ float bfhi(uint v) { return __uint_as_float(v & 0xffff0000u); }

// ---------------- fp32 -> bf16 conversion ----------------
__global__ void f2b(const float4* __restrict__ in, uint2* __restrict__ out, int n4) {
    int i = blockIdx.x * blockDim.x + threadIdx.x;
    int stride = gridDim.x * blockDim.x;
    for (; i < n4; i += stride) {
        float4 v = in[i];
        uint2 o;
        o.x = f2bf(v.x) | (f2bf(v.y) << 16);
        o.y = f2bf(v.z) | (f2bf(v.w) << 16);
        out[i] = o;
    }
}

// ---------------- CSR build via two-pass counting sort ----------------

// coarse bucket histogram (LDS-aggregated)
__global__ void bhist3(const int* __restrict__ e0, const int* __restrict__ e1,
                       const int* __restrict__ e2, int E, int NB, int* __restrict__ bcnt) {
    int m = blockIdx.y;
    const int* dst = (m == 0 ? e0 : (m == 1 ? e1 : e2)) + E;
    __shared__ int h[NBMAX];
    int tid = threadIdx.x;
    if (tid < NB) h[tid] = 0;
    __syncthreads();
    int i = blockIdx.x * blockDim.x + tid, st = gridDim.x * blockDim.x;
    for (; i < E; i += st) atomicAdd(&h[dst[i] >> BSH], 1);
    __syncthreads();
    if (tid < NB && h[tid]) atomicAdd(&bcnt[m * NB + tid], h[tid]);
}

// tiny serial scan of 3*NB bucket totals -> bucket start offsets + fill cursors
__global__ void bscan(const int* __restrict__ bcnt, int* __restrict__ bso,
                      int* __restrict__ gcur, int NB) {
    int m = threadIdx.x;
    if (m >= 3) return;
    int acc = 0;
    for (int b = 0; b < NB; ++b) {
        bso[m * (NB + 1) + b] = acc;
        gcur[m * NB + b] = acc;
        acc += bcnt[m * NB + b];
    }
    bso[m * (NB + 1) + NB] = acc;
}

// bin edges into bucket regions; per-(block,bucket) contiguous runs
#define BIN_CH 16
__global__ __launch_bounds__(256) void bin3(const int* __restrict__ e0, const int* __restrict__ e1,
                                            const int* __restrict__ e2, int E, int NB,
                                            int* __restrict__ gcur, int2* __restrict__ pairs) {
    int m = blockIdx.y;
    const int* eb = (m == 0 ? e0 : (m == 1 ? e1 : e2));
    const int* src = eb;
    const int* dst = eb + E;
    int2* pp = pairs + (size_t)m * E;
    int* gc = gcur + m * NB;
    __shared__ int h[NBMAX], base[NBMAX], pos[NBMAX];
    int tid = threadIdx.x;
    if (tid < NB) { h[tid] = 0; pos[tid] = 0; }
    __syncthreads();
    int i0 = blockIdx.x * (256 * BIN_CH);
    int sv[BIN_CH], dv[BIN_CH], bk[BIN_CH];
    #pragma unroll
    for (int u = 0; u < BIN_CH; ++u) {
        int i = i0 + u * 256 + tid;
        bk[u] = -1;
        if (i < E) {
            sv[u] = src[i];
            dv[u] = dst[i];
            bk[u] = dv[u] >> BSH;
            atomicAdd(&h[bk[u]], 1);
        }
    }
    __syncthreads();
    if (tid < NB && h[tid]) base[tid] = atomicAdd(&gc[tid], h[tid]);
    __syncthreads();
    #pragma unroll
    for (int u = 0; u < BIN_CH; ++u) {
        if (bk[u] >= 0) {
            int p = base[bk[u]] + atomicAdd(&pos[bk[u]], 1);
            pp[p] = make_int2(sv[u], dv[u]);
        }
    }
}

// per-bucket fine CSR: LDS histogram + scan + scatter, coalesced output
__global__ __launch_bounds__(256) void csr3(const int2* __restrict__ pairs, const int* __restrict__ bso,
                                            int E, int N, int NB,
                                            int* __restrict__ offs, int* __restrict__ srcs) {
    int m = blockIdx.y, b = blockIdx.x;
    const int2* pp = pairs + (size_t)m * E;
    int gstart = bso[m * (NB + 1) + b];
    int gend = bso[m * (NB + 1) + b + 1];
    int cnt = gend - gstart;
    if (cnt > BCAP) cnt = BCAP;
    int d0 = b << BSH;
    int dcnt = N - d0;
    if (dcnt > (1 << BSH)) dcnt = 1 << BSH;

    __shared__ int hist[1 << BSH], po[1 << BSH], off0[1 << BSH];
    __shared__ int lsort[BCAP];
    __shared__ int wsum[4];
    int tid = threadIdx.x;
    hist[tid] = 0;
    hist[tid + 256] = 0;
    __syncthreads();
    for (int i = tid; i < cnt; i += 256) atomicAdd(&hist[pp[gstart + i].y - d0], 1);
    __syncthreads();
    // exclusive scan of 512 counters (thread owns 2)
    int a = hist[2 * tid], b2 = hist[2 * tid + 1];
    int s = a + b2;
    int lane = tid & 63, w = tid >> 6;
    #pragma unroll
    for (int o = 1; o < 64; o <<= 1) {
        int v = __shfl_up(s, o, 64);
        if (lane >= o) s += v;
    }
    if (lane == 63) wsum[w] = s;
    __syncthreads();
    int wp = 0;
    #pragma unroll
    for (int q = 0; q < 4; ++q)
        if (q < w) wp += wsum[q];
    int excl = wp + s - a - b2;
    off0[2 * tid] = excl; off0[2 * tid + 1] = excl + a;
    po[2 * tid] = excl;   po[2 * tid + 1] = excl + a;
    __syncthreads();
    // global offs
    for (int j = tid; j < dcnt; j += 256) offs[(size_t)m * (N + 1) + d0 + j] = gstart + off0[j];
    if (b == NB - 1 && tid == 0) offs[(size_t)m * (N + 1) + N] = bso[m * (NB + 1) + NB];
    // scatter srcs within LDS
    for (int i = tid; i < cnt; i += 256) {
        int2 e = pp[gstart + i];
        int p = atomicAdd(&po[e.y - d0], 1);
        if (p < BCAP) lsort[p] = e.x;
    }
    __syncthreads();
    for (int i = tid; i < cnt; i += 256) srcs[(size_t)m * E + gstart + i] = lsort[i];
}

// ---------------- segment mean (CSR, bf16 in / bf16 out), 3 types batched ----------------
__global__ void agg3(const ushort* __restrict__ s0, const ushort* __restrict__ s1,
                     const ushort* __restrict__ s2,
                     uint* __restrict__ o0, uint* __restrict__ o1, uint* __restrict__ o2,
                     const int* __restrict__ offs, const int* __restrict__ srcs,
                     int n, int E) {
    int m = blockIdx.y;
    const uint* x = (const uint*)(m == 0 ? s0 : (m == 1 ? s1 : s2));
    uint* o = (m == 0 ? o0 : (m == 1 ? o1 : o2));
    const int* off = offs + (size_t)m * (n + 1);
    const int* sl = srcs + (size_t)m * E;

    int row = blockIdx.x * 4 + (threadIdx.x >> 6);
    int lane = threadIdx.x & 63;
    if (row >= n) return;
    int s = off[row], e = off[row + 1];
    float ax = 0.f, ay = 0.f;
    int i = s;
    for (; i + 3 < e; i += 4) {
        int i0 = sl[i], i1 = sl[i + 1], i2 = sl[i + 2], i3 = sl[i + 3];
        uint v0 = x[(size_t)i0 * 64 + lane];
        uint v1 = x[(size_t)i1 * 64 + lane];
        uint v2 = x[(size_t)i2 * 64 + lane];
        uint v3 = x[(size_t)i3 * 64 + lane];
        ax += (bflo(v0) + bflo(v1)) + (bflo(v2) + bflo(v3));
        ay += (bfhi(v0) + bfhi(v1)) + (bfhi(v2) + bfhi(v3));
    }
    for (; i < e; ++i) {
        uint v0 = x[(size_t)sl[i] * 64 + lane];
        ax += bflo(v0);
        ay += bfhi(v0);
    }
    int d = e - s;
    float inv = 1.f / (float)(d > 0 ? d : 1);
    o[(size_t)row * 64 + lane] = f2bf(ax * inv) | (f2bf(ay * inv) << 16);
}

// ---------------- weight fusion: all 10 effective matrices in one dispatch ----------------
// job j5 = l*5 + t;  t: 0=FA0 1=FA1 2=FA2 3=FB1 4=FB0(2 terms). Output bf16 transposed [n][k].
__global__ void fuseW(const float* __restrict__ Wn1, const float* __restrict__ Ws1,
                      const float* __restrict__ Wu1,
                      const float* __restrict__ Wn2, const float* __restrict__ Ws2,
                      const float* __restrict__ Wu2, ushort* __restrict__ FT) {
    int j5 = blockIdx.y;
    int l = j5 / 5, t = j5 - l * 5;
    const float* Wn = l ? Wn2 : Wn1;
    const float* Ws = l ? Ws2 : Ws1;
    const float* Wu = l ? Wu2 : Wu1;
    const float *A0, *B0, *A1 = nullptr, *B1 = nullptr;
    float al;
    switch (t) {
        case 0: A0 = Wn;          B0 = Wu;          al = 1.0f; break;
        case 1: A0 = Wn + 16384;  B0 = Wu + 32768;  al = 0.5f; break;
        case 2: A0 = Wn + 32768;  B0 = Wu + 65536;  al = 0.5f; break;
        case 3: A0 = Ws;          B0 = Wu + 16384;  al = 1.0f; break;
        default:
            A0 = Ws + 16384; B0 = Wu + 49152;
            A1 = Ws + 32768; B1 = Wu + 81920;
            al = 0.5f; break;
    }
    int i = blockIdx.x, j = threadIdx.x;
    float s0 = 0, s1 = 0, s2 = 0, s3 = 0;
    #pragma unroll 4
    for (int k = 0; k < 128; k += 4) {
        s0 += A0[i * 128 + k]     * B0[k * 128 + j];
        s1 += A0[i * 128 + k + 1] * B0[(k + 1) * 128 + j];
        s2 += A0[i * 128 + k + 2] * B0[(k + 2) * 128 + j];
        s3 += A0[i * 128 + k + 3] * B0[(k + 3) * 128 + j];
    }
    if (A1) {
        #pragma unroll 4
        for (int k = 0; k < 128; k += 4) {
            s0 += A1[i * 128 + k]     * B1[k * 128 + j];
            s1 += A1[i * 128 + k + 1] * B1[(k + 1) * 128 + j];
            s2 += A1[i * 128 + k + 2] * B1[(k + 2) * 128 + j];
            s3 += A1[i * 128 + k + 3] * B1[(k + 3) * 128 + j];
        }
    }
    float r = al * ((s0 + s1) + (s2 + s3));
    FT[(size_t)j5 * 16384 + j * 128 + i] = (ushort)f2bf(r);
}

// fused bias vectors: jb = l*2 + which (0 = fcH1, 1 = fcH0)
__global__ void fuseB(const float* __restrict__ bn1, const float* __restrict__ bs1,
                      const float* __restrict__ bu1, const float* __restrict__ Wu1,
                      const float* __restrict__ bn2, const float* __restrict__ bs2,
                      const float* __restrict__ bu2, const float* __restrict__ Wu2,
                      float* __restrict__ FC) {
    int jb = blockIdx.x;
    int l = jb >> 1, which = jb & 1;
    const float* bn = l ? bn2 : bn1;
    const float* bs = l ? bs2 : bs1;
    const float* bu = l ? bu2 : bu1;
    const float* Wu = l ? Wu2 : Wu1;
    int j = threadIdx.x;
    float s = 0.f;
    if (which == 0) {
        s = bu[j];
        for (int k = 0; k < 128; ++k)
            s += bn[k] * Wu[k * 128 + j] + bs[k] * Wu[(128 + k) * 128 + j];
    } else {
        #pragma unroll
        for (int tt = 1; tt <= 2; ++tt) {
            const float* Wt = Wu + tt * 32768;
            float p = bu[tt * 128 + j];
            for (int k = 0; k < 128; ++k)
                p += bn[tt * 128 + k] * Wt[k * 128 + j] + bs[tt * 128 + k] * Wt[(128 + k) * 128 + j];
            s += 0.5f * p;
        }
    }
    FC[jb * 128 + j] = s;
}

// ---------------- MFMA GEMM: C[M,128] = sum_i A_i[M,128]@W_i + bias, + BN col stats ----------------
#define APITCH 136
__global__ __launch_bounds__(256) void gemm_mfma(
    const ushort* __restrict__ A0, const ushort* __restrict__ W0,
    const ushort* __restrict__ A1, const ushort* __restrict__ W1,
    const ushort* __restrict__ A2, const ushort* __restrict__ W2,
    int nIn, const float* __restrict__ bias, float* __restrict__ C, int M,
    float* __restrict__ colsum, float* __restrict__ colsq) {
    __shared__ ushort As[64 * APITCH];
    int tid = threadIdx.x;
    int wid = tid >> 6;
    int lane = tid & 63;
    int l15 = lane & 15, lg = lane >> 4;
    int row0 = blockIdx.x * 64;

    f32x4 acc[4][2];
    #pragma unroll
    for (int rb = 0; rb < 4; ++rb)
        #pragma unroll
        for (int cb = 0; cb < 2; ++cb) acc[rb][cb] = (f32x4){0.f, 0.f, 0.f, 0.f};

    for (int inp = 0; inp < nIn; ++inp) {
        const ushort* A = (inp == 0) ? A0 : ((inp == 1) ? A1 : A2);
        const ushort* W = (inp == 0) ? W0 : ((inp == 1) ? W1 : W2);
        __syncthreads();
        {
            int r = tid >> 4;
            int c8 = (tid & 15) * 8;
            #pragma unroll
            for (int p = 0; p < 4; ++p) {
                int rr = p * 16 + r;
                int gr = row0 + rr;
                uint4 v = make_uint4(0, 0, 0, 0);
                if (gr < M) v = *(const uint4*)(A + (size_t)gr * 128 + c8);
                *(uint4*)(&As[rr * APITCH + c8]) = v;
            }
        }
        __syncthreads();
        #pragma unroll
        for (int k0 = 0; k0 < 128; k0 += 32) {
            int ka = k0 + lg * 8;
            short8 a[4], b[2];
            #pragma unroll
            for (int rb = 0; rb < 4; ++rb)
                a[rb] = *(const short8*)(&As[(rb * 16 + l15) * APITCH + ka]);
            #pragma unroll
            for (int cb = 0; cb < 2; ++cb) {
                int col = wid * 32 + cb * 16 + l15;
                b[cb] = *(const short8*)(W + (size_t)col * 128 + ka);
            }
            #pragma unroll
            for (int rb = 0; rb < 4; ++rb)
                #pragma unroll
                for (int cb = 0; cb < 2; ++cb)
                    acc[rb][cb] = __builtin_amdgcn_mfma_f32_16x16x32_bf16(a[rb], b[cb], acc[rb][cb], 0, 0, 0);
        }
    }

    float ps[2] = {0.f, 0.f}, pq[2] = {0.f, 0.f};
    int colbase = wid * 32;
    #pragma unroll
    for (int cb = 0; cb < 2; ++cb) {
        int col = colbase + cb * 16 + l15;
        float b = bias[col];
        #pragma unroll
        for (int rb = 0; rb < 4; ++rb) {
            int rbase = row0 + rb * 16 + lg * 4;
            #pragma unroll
            for (int i = 0; i < 4; ++i) {
                int r = rbase + i;
                if (r < M) {
                    float v = acc[rb][cb][i] + b;
                    C[(size_t)r * 128 + col] = v;
                    ps[cb] += v;
                    pq[cb] += v * v;
                }
            }
        }
    }
    #pragma unroll
    for (int cb = 0; cb < 2; ++cb) {
        ps[cb] += __shfl_xor(ps[cb], 16, 64);
        ps[cb] += __shfl_xor(ps[cb], 32, 64);
        pq[cb] += __shfl_xor(pq[cb], 16, 64);
        pq[cb] += __shfl_xor(pq[cb], 32, 64);
    }
    if (lane < 16) {
        atomicAdd(&colsum[colbase + lane], ps[0]);
        atomicAdd(&colsq[colbase + lane], pq[0]);
        atomicAdd(&colsum[colbase + 16 + lane], ps[1]);
        atomicAdd(&colsq[colbase + 16 + lane], pq[1]);
    }
}

// ---------------- BN finalize (self-zeroing stats for next layer) ----------------
__global__ void bn_fin(float* __restrict__ colsum, float* __restrict__ colsq,
                       const float* __restrict__ gamma, const float* __restrict__ beta,
                       float* __restrict__ scale, float* __restrict__ shift, int N) {
    int c = threadIdx.x;
    float m = colsum[c] / (float)N;
    float v = colsq[c] / (float)N - m * m;
    float rs = rsqrtf(v + 1e-5f);
    float sc = gamma[c] * rs;
    scale[c] = sc;
    shift[c] = beta[c] - m * sc;
    colsum[c] = 0.f;
    colsq[c] = 0.f;
}

__global__ void bn_apply_b(const float4* __restrict__ in, uint2* __restrict__ out,
                           const float* __restrict__ scale, const float* __restrict__ shift, int n4) {
    int i = blockIdx.x * blockDim.x + threadIdx.x;
    int stride = gridDim.x * blockDim.x;
    for (; i < n4; i += stride) {
        float4 v = in[i];
        int cb = (i * 4) & 127;
        float4 sc = *(const float4*)&scale[cb];
        float4 sh = *(const float4*)&shift[cb];
        float y0 = v.x * sc.x + sh.x;
        float y1 = v.y * sc.y + sh.y;
        float y2 = v.z * sc.z + sh.z;
        float y3 = v.w * sc.w + sh.w;
        y0 = (y0 >= 0.f) ? y0 : 0.01f * y0;
        y1 = (y1 >= 0.f) ? y1 : 0.01f * y1;
        y2 = (y2 >= 0.f) ? y2 : 0.01f * y2;
        y3 = (y3 >= 0.f) ? y3 : 0.01f * y3;
        uint2 o;
        o.x = f2bf(y0) | (f2bf(y1) << 16);
        o.y = f2bf(y2) | (f2bf(y3) << 16);
        out[i] = o;
    }
}

// ---------------- final projection [N,128]bf16 @ [128,8] + b ----------------
__global__ void proj_b(const uint* __restrict__ h, const float* __restrict__ Wp,
                       const float* __restrict__ bp, float* __restrict__ out, int N) {
    __shared__ float Wsh[1024];
    __shared__ float bsh[8];
    int tid = threadIdx.x;
    for (int i = tid; i < 1024; i += 256) Wsh[i] = Wp[i];
    if (tid < 8) bsh[tid] = bp[tid];
    __syncthreads();
    int idx = blockIdx.x * 256 + tid;
    if (idx >= N * LBL) return;
    int r = idx >> 3, c = idx & 7;
    const uint* hr = h + (size_t)r * 64;
    float s = bsh[c];
    #pragma unroll
    for (int k2 = 0; k2 < 64; ++k2) {
        uint v = hr[k2];
        s += bflo(v) * Wsh[(2 * k2) * 8 + c] + bfhi(v) * Wsh[(2 * k2 + 1) * 8 + c];
    }
    out[idx] = s;
}

// ---------------- host ----------------

extern "C" void kernel_launch(void* const* d_in, const int* in_sizes, int n_in,
                              void* d_out, int out_size, void* d_ws, size_t ws_size,
                              hipStream_t stream) {
    const float* x0 = (const float*)d_in[0];
    const float* x1 = (const float*)d_in[1];
    const float* Wn1 = (const float*)d_in[2];
    const float* Ws1 = (const float*)d_in[3];
    const float* Wu1 = (const float*)d_in[4];
    const float* Wn2 = (const float*)d_in[5];
    const float* Ws2 = (const float*)d_in[6];
    const float* Wu2 = (const float*)d_in[7];
    const float* bnn[2] = {(const float*)d_in[8], (const float*)d_in[11]};
    const float* bss[2] = {(const float*)d_in[9], (const float*)d_in[12]};
    const float* buu[2] = {(const float*)d_in[10], (const float*)d_in[13]};
    const float* gam[2] = {(const float*)d_in[14], (const float*)d_in[16]};
    const float* bet[2] = {(const float*)d_in[15], (const float*)d_in[17]};
    const float* Wp = (const float*)d_in[18];
    const float* bp = (const float*)d_in[19];
    const int* ei[3] = {(const int*)d_in[20], (const int*)d_in[21], (const int*)d_in[22]};

    const int N = in_sizes[0] / 128;
    const int E = in_sizes[20] / 2;
    const int NB = (N + (1 << BSH) - 1) >> BSH;
    float* out = (float*)d_out;

    // ---- workspace carve ----
    char* wp_ = (char*)d_ws;
    auto carve = [&](size_t bytes) {
        char* r = wp_;
        wp_ += (bytes + 255) & ~(size_t)255;
        return r;
    };
    size_t nodeF = (size_t)N * 128 * sizeof(float);
    size_t nodeB = (size_t)N * 128 * sizeof(ushort);
    float* Cp = (float*)carve(nodeF);      // h0pre fp32 (pairs aliases this, dead by then)
    float* Cq = (float*)carve(nodeF);      // h1pre fp32
    ushort* Pb = (ushort*)carve(nodeB);
    ushort* Rb = (ushort*)carve(nodeB);
    ushort* Sb = (ushort*)carve(nodeB);
    ushort* X0b = (ushort*)carve(nodeB);
    ushort* X1b = (ushort*)carve(nodeB);
    ushort* x0b = (ushort*)carve(nodeB);
    ushort* x1b = (ushort*)carve(nodeB);
    ushort* FT = (ushort*)carve(10 * 16384 * 2);  // 10 fused weight mats, bf16 [n][k]
    float* FC = (float*)carve(4 * 128 * 4);       // 4 fused bias vectors
    float* ST = (float*)carve(1024 * 4);
    int* offs = (int*)carve((size_t)3 * (N + 1) * 4);
    int* srcs = (int*)carve((size_t)3 * E * 4);
    int* bcnt = (int*)carve((size_t)3 * NB * 4);
    int* bso = (int*)carve((size_t)3 * (NB + 1) * 4);
    int* gcur = (int*)carve((size_t)3 * NB * 4);
    int2* pairs = (int2*)Cp;  // 3*E*8 = 12 MB <= nodeF (25.6 MB); dead before gemm writes Cp

    float* SC0 = ST + 512; float* SH0 = ST + 640;
    float* SC1 = ST + 768; float* SH1 = ST + 896;

    const int ag = (N + 3) / 4;
    const int gg = (N + 63) / 64;
    const int pg = (N * LBL + 255) / 256;
    const int bg = (E + 256 * BIN_CH - 1) / (256 * BIN_CH);

    // ---- input bf16 conversion ----
    f2b<<<2048, 256, 0, stream>>>((const float4*)x0, (uint2*)x0b, N * 32);
    f2b<<<2048, 256, 0, stream>>>((const float4*)x1, (uint2*)x1b, N * 32);

    // ---- CSR build (counting sort; shared by both layers) ----
    hipMemsetAsync(bcnt, 0, (size_t)3 * NB * 4, stream);
    bhist3<<<dim3(512, 3), 256, 0, stream>>>(ei[0], ei[1], ei[2], E, NB, bcnt);
    bscan<<<1, 64, 0, stream>>>(bcnt, bso, gcur, NB);
    bin3<<<dim3(bg, 3), 256, 0, stream>>>(ei[0], ei[1], ei[2], E, NB, gcur, pairs);
    csr3<<<dim3(NB, 3), 256, 0, stream>>>(pairs, bso, E, N, NB, offs, srcs);

    // ---- fuse all weights/biases up front (inputs-only dependence) ----
    fuseW<<<dim3(128, 10), 128, 0, stream>>>(Wn1, Ws1, Wu1, Wn2, Ws2, Wu2, FT);
    fuseB<<<4, 128, 0, stream>>>(bnn[0], bss[0], buu[0], Wu1, bnn[1], bss[1], buu[1], Wu2, FC);

    hipMemsetAsync(ST, 0, 512 * 4, stream);

    const ushort* srcS[2][3] = {{x0b, x1b, x0b}, {X0b, X1b, X0b}};
    const ushort* dstX[2][2] = {{x0b, x1b}, {X0b, X1b}};

    for (int l = 0; l < 2; ++l) {
        const ushort* FA0T = FT + (size_t)(l * 5 + 0) * 16384;
        const ushort* FA1T = FT + (size_t)(l * 5 + 1) * 16384;
        const ushort* FA2T = FT + (size_t)(l * 5 + 2) * 16384;
        const ushort* FB1T = FT + (size_t)(l * 5 + 3) * 16384;
        const ushort* FB0T = FT + (size_t)(l * 5 + 4) * 16384;
        const float* fcH1 = FC + (l * 2 + 0) * 128;
        const float* fcH0 = FC + (l * 2 + 1) * 128;

        agg3<<<dim3(ag, 3), 256, 0, stream>>>(srcS[l][0], srcS[l][1], srcS[l][2],
                                              (uint*)Pb, (uint*)Rb, (uint*)Sb,
                                              offs, srcs, N, E);

        gemm_mfma<<<gg, 256, 0, stream>>>(Pb, FA0T, dstX[l][1], FB1T, nullptr, nullptr,
                                          2, fcH1, Cq, N, ST + 256, ST + 384);
        gemm_mfma<<<gg, 256, 0, stream>>>(Rb, FA1T, Sb, FA2T, dstX[l][0], FB0T,
                                          3, fcH0, Cp, N, ST, ST + 128);

        bn_fin<<<1, 128, 0, stream>>>(ST,       ST + 128, gam[l],       bet[l],       SC0, SH0, N);
        bn_fin<<<1, 128, 0, stream>>>(ST + 256, ST + 384, gam[l] + 128, bet[l] + 128, SC1, SH1, N);
        bn_apply_b<<<2048, 256, 0, stream>>>((const float4*)Cp, (uint2*)X0b, SC0, SH0, N * 32);
        bn_apply_b<<<2048, 256, 0, stream>>>((const float4*)Cq, (uint2*)X1b, SC1, SH1, N * 32);
    }

    proj_b<<<pg, 256, 0, stream>>>((const uint*)X0b, Wp,        bp,     out,                 N);
    proj_b<<<pg, 256, 0, stream>>>((const uint*)X1b, Wp + 1024, bp + 8, out + (size_t)N * 8, N);
}

// Round 4
// 356.247 us; speedup vs baseline: 2.7287x; 1.2540x over previous
//
#include <hip/hip_runtime.h>

#define LBL 8
#define NBMAX 128
#define BSH 9            // 512 dsts per bucket
#define BCAP 8192        // LDS sort capacity per bucket (mean ~5100)

typedef __attribute__((ext_vector_type(8))) short short8;
typedef __attribute__((ext_vector_type(4))) float f32x4;

__device__ __forceinline__ uint f2bf(float x) {
    uint u = __float_as_uint(x);
    return (u + 0x7fffu + ((u >> 16) & 1u)) >> 16;
}
__device__ __forceinline__ float bflo(uint v) { return __uint_as_float(v << 16); }
__device__ __forceinline__ float bfhi(uint v) { return __uint_as_float(v & 0xffff0000u); }

// ---------------- fp32 -> bf16 conversion (both node types, one dispatch) ----------------
__global__ void f2b2(const float4* __restrict__ x0, const float4* __restrict__ x1,
                     uint2* __restrict__ o0, uint2* __restrict__ o1, int n4) {
    int y = blockIdx.y;
    const float4* in = y ? x1 : x0;
    uint2* out = y ? o1 : o0;
    int i = blockIdx.x * blockDim.x + threadIdx.x;
    int stride = gridDim.x * blockDim.x;
    for (; i < n4; i += stride) {
        float4 v = in[i];
        uint2 o;
        o.x = f2bf(v.x) | (f2bf(v.y) << 16);
        o.y = f2bf(v.z) | (f2bf(v.w) << 16);
        out[i] = o;
    }
}

// ---------------- CSR build via two-pass counting sort ----------------

__global__ void bhist3(const int* __restrict__ e0, const int* __restrict__ e1,
                       const int* __restrict__ e2, int E, int NB, int* __restrict__ bcnt) {
    int m = blockIdx.y;
    const int* dst = (m == 0 ? e0 : (m == 1 ? e1 : e2)) + E;
    __shared__ int h[NBMAX];
    int tid = threadIdx.x;
    if (tid < NB) h[tid] = 0;
    __syncthreads();
    int i = blockIdx.x * blockDim.x + tid, st = gridDim.x * blockDim.x;
    for (; i < E; i += st) atomicAdd(&h[dst[i] >> BSH], 1);
    __syncthreads();
    if (tid < NB && h[tid]) atomicAdd(&bcnt[m * NB + tid], h[tid]);
}

__global__ void bscan(const int* __restrict__ bcnt, int* __restrict__ bso,
                      int* __restrict__ gcur, int NB) {
    int m = threadIdx.x;
    if (m >= 3) return;
    int acc = 0;
    for (int b = 0; b < NB; ++b) {
        bso[m * (NB + 1) + b] = acc;
        gcur[m * NB + b] = acc;
        acc += bcnt[m * NB + b];
    }
    bso[m * (NB + 1) + NB] = acc;
}

#define BIN_CH 16
__global__ __launch_bounds__(256) void bin3(const int* __restrict__ e0, const int* __restrict__ e1,
                                            const int* __restrict__ e2, int E, int NB,
                                            int* __restrict__ gcur, int2* __restrict__ pairs) {
    int m = blockIdx.y;
    const int* eb = (m == 0 ? e0 : (m == 1 ? e1 : e2));
    const int* src = eb;
    const int* dst = eb + E;
    int2* pp = pairs + (size_t)m * E;
    int* gc = gcur + m * NB;
    __shared__ int h[NBMAX], base[NBMAX], pos[NBMAX];
    int tid = threadIdx.x;
    if (tid < NB) { h[tid] = 0; pos[tid] = 0; }
    __syncthreads();
    int i0 = blockIdx.x * (256 * BIN_CH);
    int sv[BIN_CH], dv[BIN_CH], bk[BIN_CH];
    #pragma unroll
    for (int u = 0; u < BIN_CH; ++u) {
        int i = i0 + u * 256 + tid;
        bk[u] = -1;
        if (i < E) {
            sv[u] = src[i];
            dv[u] = dst[i];
            bk[u] = dv[u] >> BSH;
            atomicAdd(&h[bk[u]], 1);
        }
    }
    __syncthreads();
    if (tid < NB && h[tid]) base[tid] = atomicAdd(&gc[tid], h[tid]);
    __syncthreads();
    #pragma unroll
    for (int u = 0; u < BIN_CH; ++u) {
        if (bk[u] >= 0) {
            int p = base[bk[u]] + atomicAdd(&pos[bk[u]], 1);
            pp[p] = make_int2(sv[u], dv[u]);
        }
    }
}

__global__ __launch_bounds__(256) void csr3(const int2* __restrict__ pairs, const int* __restrict__ bso,
                                            int E, int N, int NB,
                                            int* __restrict__ offs, int* __restrict__ srcs) {
    int m = blockIdx.y, b = blockIdx.x;
    const int2* pp = pairs + (size_t)m * E;
    int gstart = bso[m * (NB + 1) + b];
    int gend = bso[m * (NB + 1) + b + 1];
    int cnt = gend - gstart;
    if (cnt > BCAP) cnt = BCAP;
    int d0 = b << BSH;
    int dcnt = N - d0;
    if (dcnt > (1 << BSH)) dcnt = 1 << BSH;

    __shared__ int hist[1 << BSH], po[1 << BSH], off0[1 << BSH];
    __shared__ int lsort[BCAP];
    __shared__ int wsum[4];
    int tid = threadIdx.x;
    hist[tid] = 0;
    hist[tid + 256] = 0;
    __syncthreads();
    for (int i = tid; i < cnt; i += 256) atomicAdd(&hist[pp[gstart + i].y - d0], 1);
    __syncthreads();
    int a = hist[2 * tid], b2 = hist[2 * tid + 1];
    int s = a + b2;
    int lane = tid & 63, w = tid >> 6;
    #pragma unroll
    for (int o = 1; o < 64; o <<= 1) {
        int v = __shfl_up(s, o, 64);
        if (lane >= o) s += v;
    }
    if (lane == 63) wsum[w] = s;
    __syncthreads();
    int wp = 0;
    #pragma unroll
    for (int q = 0; q < 4; ++q)
        if (q < w) wp += wsum[q];
    int excl = wp + s - a - b2;
    off0[2 * tid] = excl; off0[2 * tid + 1] = excl + a;
    po[2 * tid] = excl;   po[2 * tid + 1] = excl + a;
    __syncthreads();
    for (int j = tid; j < dcnt; j += 256) offs[(size_t)m * (N + 1) + d0 + j] = gstart + off0[j];
    if (b == NB - 1 && tid == 0) offs[(size_t)m * (N + 1) + N] = bso[m * (NB + 1) + NB];
    for (int i = tid; i < cnt; i += 256) {
        int2 e = pp[gstart + i];
        int p = atomicAdd(&po[e.y - d0], 1);
        if (p < BCAP) lsort[p] = e.x;
    }
    __syncthreads();
    for (int i = tid; i < cnt; i += 256) srcs[(size_t)m * E + gstart + i] = lsort[i];
}

// ---------------- segment mean: 4 rows/wave (16 lanes x uint4 = 256B row) ----------------
__global__ void agg3(const ushort* __restrict__ s0, const ushort* __restrict__ s1,
                     const ushort* __restrict__ s2,
                     uint* __restrict__ o0, uint* __restrict__ o1, uint* __restrict__ o2,
                     const int* __restrict__ offs, const int* __restrict__ srcs,
                     int n, int E) {
    int m = blockIdx.y;
    const uint4* x = (const uint4*)(m == 0 ? s0 : (m == 1 ? s1 : s2));
    uint4* o = (uint4*)(m == 0 ? o0 : (m == 1 ? o1 : o2));
    const int* off = offs + (size_t)m * (n + 1);
    const int* sl = srcs + (size_t)m * E;

    int tid = threadIdx.x;
    int l16 = tid & 15;
    int row = blockIdx.x * 16 + (tid >> 4);
    if (row >= n) return;
    int s = off[row], e = off[row + 1];
    float a0 = 0, a1 = 0, a2 = 0, a3 = 0, a4 = 0, a5 = 0, a6 = 0, a7 = 0;
    int i = s;
    for (; i + 1 < e; i += 2) {
        uint4 v0 = x[(size_t)sl[i] * 16 + l16];
        uint4 v1 = x[(size_t)sl[i + 1] * 16 + l16];
        a0 += bflo(v0.x) + bflo(v1.x); a1 += bfhi(v0.x) + bfhi(v1.x);
        a2 += bflo(v0.y) + bflo(v1.y); a3 += bfhi(v0.y) + bfhi(v1.y);
        a4 += bflo(v0.z) + bflo(v1.z); a5 += bfhi(v0.z) + bfhi(v1.z);
        a6 += bflo(v0.w) + bflo(v1.w); a7 += bfhi(v0.w) + bfhi(v1.w);
    }
    if (i < e) {
        uint4 v0 = x[(size_t)sl[i] * 16 + l16];
        a0 += bflo(v0.x); a1 += bfhi(v0.x);
        a2 += bflo(v0.y); a3 += bfhi(v0.y);
        a4 += bflo(v0.z); a5 += bfhi(v0.z);
        a6 += bflo(v0.w); a7 += bfhi(v0.w);
    }
    int d = e - s;
    float inv = 1.f / (float)(d > 0 ? d : 1);
    uint4 r;
    r.x = f2bf(a0 * inv) | (f2bf(a1 * inv) << 16);
    r.y = f2bf(a2 * inv) | (f2bf(a3 * inv) << 16);
    r.z = f2bf(a4 * inv) | (f2bf(a5 * inv) << 16);
    r.w = f2bf(a6 * inv) | (f2bf(a7 * inv) << 16);
    o[(size_t)row * 16 + l16] = r;
}

// ---------------- weight fusion ----------------
__global__ void fuseW(const float* __restrict__ Wn1, const float* __restrict__ Ws1,
                      const float* __restrict__ Wu1,
                      const float* __restrict__ Wn2, const float* __restrict__ Ws2,
                      const float* __restrict__ Wu2, ushort* __restrict__ FT) {
    int j5 = blockIdx.y;
    int l = j5 / 5, t = j5 - l * 5;
    const float* Wn = l ? Wn2 : Wn1;
    const float* Ws = l ? Ws2 : Ws1;
    const float* Wu = l ? Wu2 : Wu1;
    const float *A0, *B0, *A1 = nullptr, *B1 = nullptr;
    float al;
    switch (t) {
        case 0: A0 = Wn;          B0 = Wu;          al = 1.0f; break;
        case 1: A0 = Wn + 16384;  B0 = Wu + 32768;  al = 0.5f; break;
        case 2: A0 = Wn + 32768;  B0 = Wu + 65536;  al = 0.5f; break;
        case 3: A0 = Ws;          B0 = Wu + 16384;  al = 1.0f; break;
        default:
            A0 = Ws + 16384; B0 = Wu + 49152;
            A1 = Ws + 32768; B1 = Wu + 81920;
            al = 0.5f; break;
    }
    int i = blockIdx.x, j = threadIdx.x;
    float s0 = 0, s1 = 0, s2 = 0, s3 = 0;
    #pragma unroll 4
    for (int k = 0; k < 128; k += 4) {
        s0 += A0[i * 128 + k]     * B0[k * 128 + j];
        s1 += A0[i * 128 + k + 1] * B0[(k + 1) * 128 + j];
        s2 += A0[i * 128 + k + 2] * B0[(k + 2) * 128 + j];
        s3 += A0[i * 128 + k + 3] * B0[(k + 3) * 128 + j];
    }
    if (A1) {
        #pragma unroll 4
        for (int k = 0; k < 128; k += 4) {
            s0 += A1[i * 128 + k]     * B1[k * 128 + j];
            s1 += A1[i * 128 + k + 1] * B1[(k + 1) * 128 + j];
            s2 += A1[i * 128 + k + 2] * B1[(k + 2) * 128 + j];
            s3 += A1[i * 128 + k + 3] * B1[(k + 3) * 128 + j];
        }
    }
    float r = al * ((s0 + s1) + (s2 + s3));
    FT[(size_t)j5 * 16384 + j * 128 + i] = (ushort)f2bf(r);
}

__global__ void fuseB(const float* __restrict__ bn1, const float* __restrict__ bs1,
                      const float* __restrict__ bu1, const float* __restrict__ Wu1,
                      const float* __restrict__ bn2, const float* __restrict__ bs2,
                      const float* __restrict__ bu2, const float* __restrict__ Wu2,
                      float* __restrict__ FC) {
    int jb = blockIdx.x;
    int l = jb >> 1, which = jb & 1;
    const float* bn = l ? bn2 : bn1;
    const float* bs = l ? bs2 : bs1;
    const float* bu = l ? bu2 : bu1;
    const float* Wu = l ? Wu2 : Wu1;
    int j = threadIdx.x;
    float s = 0.f;
    if (which == 0) {
        s = bu[j];
        for (int k = 0; k < 128; ++k)
            s += bn[k] * Wu[k * 128 + j] + bs[k] * Wu[(128 + k) * 128 + j];
    } else {
        #pragma unroll
        for (int tt = 1; tt <= 2; ++tt) {
            const float* Wt = Wu + tt * 32768;
            float p = bu[tt * 128 + j];
            for (int k = 0; k < 128; ++k)
                p += bn[tt * 128 + k] * Wt[k * 128 + j] + bs[tt * 128 + k] * Wt[(128 + k) * 128 + j];
            s += 0.5f * p;
        }
    }
    FC[jb * 128 + j] = s;
}

// ---------------- batched MFMA GEMM: both per-layer jobs in one dispatch ----------------
// y==0: Cq = Aq0@Wq0 + Aq1@Wq1 + biasq (nIn=2)   y==1: Cp = sum of 3 (nIn=3)
// A bf16 [M][128]; W bf16 transposed [n][k]; C bf16; BN col stats fp32.
#define APITCH 136
__global__ __launch_bounds__(256) void gemm2_mfma(
    const ushort* __restrict__ Aq0, const ushort* __restrict__ Wq0,
    const ushort* __restrict__ Aq1, const ushort* __restrict__ Wq1,
    const ushort* __restrict__ Ap0, const ushort* __restrict__ Wp0,
    const ushort* __restrict__ Ap1, const ushort* __restrict__ Wp1,
    const ushort* __restrict__ Ap2, const ushort* __restrict__ Wp2,
    const float* __restrict__ biasq, const float* __restrict__ biasp,
    ushort* __restrict__ Cq, ushort* __restrict__ Cp, int M,
    float* __restrict__ STq, float* __restrict__ STp) {
    __shared__ ushort As[64 * APITCH];
    int y = blockIdx.y;
    int nIn = y ? 3 : 2;
    const ushort* Ax[3];
    const ushort* Wx[3];
    if (y) { Ax[0] = Ap0; Wx[0] = Wp0; Ax[1] = Ap1; Wx[1] = Wp1; Ax[2] = Ap2; Wx[2] = Wp2; }
    else   { Ax[0] = Aq0; Wx[0] = Wq0; Ax[1] = Aq1; Wx[1] = Wq1; Ax[2] = Aq0; Wx[2] = Wq0; }
    const float* bias = y ? biasp : biasq;
    ushort* C = y ? Cp : Cq;
    float* colsum = y ? STp : STq;
    float* colsq = colsum + 128;

    int tid = threadIdx.x;
    int wid = tid >> 6;
    int lane = tid & 63;
    int l15 = lane & 15, lg = lane >> 4;
    int row0 = blockIdx.x * 64;

    f32x4 acc[4][2];
    #pragma unroll
    for (int rb = 0; rb < 4; ++rb)
        #pragma unroll
        for (int cb = 0; cb < 2; ++cb) acc[rb][cb] = (f32x4){0.f, 0.f, 0.f, 0.f};

    for (int inp = 0; inp < nIn; ++inp) {
        const ushort* A = Ax[inp];
        const ushort* W = Wx[inp];
        __syncthreads();
        {
            int r = tid >> 4;
            int c8 = (tid & 15) * 8;
            #pragma unroll
            for (int p = 0; p < 4; ++p) {
                int rr = p * 16 + r;
                int gr = row0 + rr;
                uint4 v = make_uint4(0, 0, 0, 0);
                if (gr < M) v = *(const uint4*)(A + (size_t)gr * 128 + c8);
                *(uint4*)(&As[rr * APITCH + c8]) = v;
            }
        }
        __syncthreads();
        #pragma unroll
        for (int k0 = 0; k0 < 128; k0 += 32) {
            int ka = k0 + lg * 8;
            short8 a[4], b[2];
            #pragma unroll
            for (int rb = 0; rb < 4; ++rb)
                a[rb] = *(const short8*)(&As[(rb * 16 + l15) * APITCH + ka]);
            #pragma unroll
            for (int cb = 0; cb < 2; ++cb) {
                int col = wid * 32 + cb * 16 + l15;
                b[cb] = *(const short8*)(W + (size_t)col * 128 + ka);
            }
            #pragma unroll
            for (int rb = 0; rb < 4; ++rb)
                #pragma unroll
                for (int cb = 0; cb < 2; ++cb)
                    acc[rb][cb] = __builtin_amdgcn_mfma_f32_16x16x32_bf16(a[rb], b[cb], acc[rb][cb], 0, 0, 0);
        }
    }

    float ps[2] = {0.f, 0.f}, pq[2] = {0.f, 0.f};
    int colbase = wid * 32;
    #pragma unroll
    for (int cb = 0; cb < 2; ++cb) {
        int col = colbase + cb * 16 + l15;
        float b = bias[col];
        #pragma unroll
        for (int rb = 0; rb < 4; ++rb) {
            int rbase = row0 + rb * 16 + lg * 4;
            #pragma unroll
            for (int i = 0; i < 4; ++i) {
                int r = rbase + i;
                if (r < M) {
                    float v = acc[rb][cb][i] + b;
                    C[(size_t)r * 128 + col] = (ushort)f2bf(v);
                    ps[cb] += v;
                    pq[cb] += v * v;
                }
            }
        }
    }
    #pragma unroll
    for (int cb = 0; cb < 2; ++cb) {
        ps[cb] += __shfl_xor(ps[cb], 16, 64);
        ps[cb] += __shfl_xor(ps[cb], 32, 64);
        pq[cb] += __shfl_xor(pq[cb], 16, 64);
        pq[cb] += __shfl_xor(pq[cb], 32, 64);
    }
    if (lane < 16) {
        atomicAdd(&colsum[colbase + lane], ps[0]);
        atomicAdd(&colsq[colbase + lane], pq[0]);
        atomicAdd(&colsum[colbase + 16 + lane], ps[1]);
        atomicAdd(&colsq[colbase + 16 + lane], pq[1]);
    }
}

// ---------------- BN finalize, both node types (self-zeroing stats) ----------------
// ST layout: [0]=sum0 [128]=sq0 [256]=sum1 [384]=sq1 [512]=SC0 [640]=SH0 [768]=SC1 [896]=SH1
__global__ void bn_fin2(float* __restrict__ ST, const float* __restrict__ g0,
                        const float* __restrict__ b0, const float* __restrict__ g1,
                        const float* __restrict__ b1, int N) {
    int tid = threadIdx.x;
    int which = tid >> 7, c = tid & 127;
    float* colsum = ST + which * 256;
    float* colsq = colsum + 128;
    const float* g = which ? g1 : g0;
    const float* b = which ? b1 : b0;
    float m = colsum[c] / (float)N;
    float v = colsq[c] / (float)N - m * m;
    float rs = rsqrtf(v + 1e-5f);
    float sc = g[c] * rs;
    ST[512 + which * 256 + c] = sc;
    ST[640 + which * 256 + c] = b[c] - m * sc;
    colsum[c] = 0.f;
    colsq[c] = 0.f;
}

// ---------------- BN apply + LeakyReLU: bf16 in -> bf16 out, both types ----------------
__global__ void bn_apply2(const ushort* __restrict__ Cp, ushort* __restrict__ X0b,
                          const ushort* __restrict__ Cq, ushort* __restrict__ X1b,
                          const float* __restrict__ ST, int n4) {
    int y = blockIdx.y;
    const uint2* in = (const uint2*)(y ? Cq : Cp);
    uint2* out = (uint2*)(y ? X1b : X0b);
    const float* sc = ST + 512 + y * 256;
    const float* sh = sc + 128;
    int i = blockIdx.x * blockDim.x + threadIdx.x;
    int stride = gridDim.x * blockDim.x;
    for (; i < n4; i += stride) {
        uint2 v = in[i];
        int cb = (i * 4) & 127;
        float4 s4 = *(const float4*)&sc[cb];
        float4 h4 = *(const float4*)&sh[cb];
        float y0 = bflo(v.x) * s4.x + h4.x;
        float y1 = bfhi(v.x) * s4.y + h4.y;
        float y2 = bflo(v.y) * s4.z + h4.z;
        float y3 = bfhi(v.y) * s4.w + h4.w;
        y0 = (y0 >= 0.f) ? y0 : 0.01f * y0;
        y1 = (y1 >= 0.f) ? y1 : 0.01f * y1;
        y2 = (y2 >= 0.f) ? y2 : 0.01f * y2;
        y3 = (y3 >= 0.f) ? y3 : 0.01f * y3;
        uint2 o;
        o.x = f2bf(y0) | (f2bf(y1) << 16);
        o.y = f2bf(y2) | (f2bf(y3) << 16);
        out[i] = o;
    }
}

// ---------------- final projection, both types ----------------
__global__ void proj2(const uint* __restrict__ X0b, const uint* __restrict__ X1b,
                      const float* __restrict__ Wp, const float* __restrict__ bp,
                      float* __restrict__ out, int N) {
    int y = blockIdx.y;
    const uint* h = y ? X1b : X0b;
    const float* W = Wp + y * 1024;
    const float* b = bp + y * 8;
    float* op = out + (size_t)y * N * 8;
    __shared__ float Wsh[1024];
    __shared__ float bsh[8];
    int tid = threadIdx.x;
    for (int i = tid; i < 1024; i += 256) Wsh[i] = W[i];
    if (tid < 8) bsh[tid] = b[tid];
    __syncthreads();
    int idx = blockIdx.x * 256 + tid;
    if (idx >= N * LBL) return;
    int r = idx >> 3, c = idx & 7;
    const uint* hr = h + (size_t)r * 64;
    float s = bsh[c];
    #pragma unroll
    for (int k2 = 0; k2 < 64; ++k2) {
        uint v = hr[k2];
        s += bflo(v) * Wsh[(2 * k2) * 8 + c] + bfhi(v) * Wsh[(2 * k2 + 1) * 8 + c];
    }
    op[idx] = s;
}

// ---------------- host ----------------

extern "C" void kernel_launch(void* const* d_in, const int* in_sizes, int n_in,
                              void* d_out, int out_size, void* d_ws, size_t ws_size,
                              hipStream_t stream) {
    const float* x0 = (const float*)d_in[0];
    const float* x1 = (const float*)d_in[1];
    const float* Wn1 = (const float*)d_in[2];
    const float* Ws1 = (const float*)d_in[3];
    const float* Wu1 = (const float*)d_in[4];
    const float* Wn2 = (const float*)d_in[5];
    const float* Ws2 = (const float*)d_in[6];
    const float* Wu2 = (const float*)d_in[7];
    const float* bnn[2] = {(const float*)d_in[8], (const float*)d_in[11]};
    const float* bss[2] = {(const float*)d_in[9], (const float*)d_in[12]};
    const float* buu[2] = {(const float*)d_in[10], (const float*)d_in[13]};
    const float* gam[2] = {(const float*)d_in[14], (const float*)d_in[16]};
    const float* bet[2] = {(const float*)d_in[15], (const float*)d_in[17]};
    const float* Wp = (const float*)d_in[18];
    const float* bp = (const float*)d_in[19];
    const int* ei[3] = {(const int*)d_in[20], (const int*)d_in[21], (const int*)d_in[22]};

    const int N = in_sizes[0] / 128;
    const int E = in_sizes[20] / 2;
    const int NB = (N + (1 << BSH) - 1) >> BSH;
    float* out = (float*)d_out;

    char* wp_ = (char*)d_ws;
    auto carve = [&](size_t bytes) {
        char* r = wp_;
        wp_ += (bytes + 255) & ~(size_t)255;
        return r;
    };
    size_t nodeB = (size_t)N * 128 * sizeof(ushort);
    ushort* Cp = (ushort*)carve(nodeB);   // h0pre bf16 (pairs aliases this early)
    ushort* Cq = (ushort*)carve(nodeB);   // h1pre bf16
    ushort* Pb = (ushort*)carve(nodeB);
    ushort* Rb = (ushort*)carve(nodeB);
    ushort* Sb = (ushort*)carve(nodeB);
    ushort* X0b = (ushort*)carve(nodeB);
    ushort* X1b = (ushort*)carve(nodeB);
    ushort* x0b = (ushort*)carve(nodeB);
    ushort* x1b = (ushort*)carve(nodeB);
    ushort* FT = (ushort*)carve(10 * 16384 * 2);
    float* FC = (float*)carve(4 * 128 * 4);
    float* ST = (float*)carve(1024 * 4);
    int* offs = (int*)carve((size_t)3 * (N + 1) * 4);
    int* srcs = (int*)carve((size_t)3 * E * 4);
    int* bcnt = (int*)carve((size_t)3 * NB * 4);
    int* bso = (int*)carve((size_t)3 * (NB + 1) * 4);
    int* gcur = (int*)carve((size_t)3 * NB * 4);
    int2* pairs = (int2*)Cp;  // 3*E*8 = 12 MB <= nodeB (12.8 MB); dead before gemm writes Cp

    const int ag = (N + 15) / 16;
    const int gg = (N + 63) / 64;
    const int pg = (N * LBL + 255) / 256;
    const int bg = (E + 256 * BIN_CH - 1) / (256 * BIN_CH);

    f2b2<<<dim3(1024, 2), 256, 0, stream>>>((const float4*)x0, (const float4*)x1,
                                            (uint2*)x0b, (uint2*)x1b, N * 32);

    hipMemsetAsync(bcnt, 0, (size_t)3 * NB * 4, stream);
    bhist3<<<dim3(512, 3), 256, 0, stream>>>(ei[0], ei[1], ei[2], E, NB, bcnt);
    bscan<<<1, 64, 0, stream>>>(bcnt, bso, gcur, NB);
    bin3<<<dim3(bg, 3), 256, 0, stream>>>(ei[0], ei[1], ei[2], E, NB, gcur, pairs);
    csr3<<<dim3(NB, 3), 256, 0, stream>>>(pairs, bso, E, N, NB, offs, srcs);

    fuseW<<<dim3(128, 10), 128, 0, stream>>>(Wn1, Ws1, Wu1, Wn2, Ws2, Wu2, FT);
    fuseB<<<4, 128, 0, stream>>>(bnn[0], bss[0], buu[0], Wu1, bnn[1], bss[1], buu[1], Wu2, FC);

    hipMemsetAsync(ST, 0, 512 * 4, stream);

    const ushort* srcS[2][3] = {{x0b, x1b, x0b}, {X0b, X1b, X0b}};
    const ushort* dstX[2][2] = {{x0b, x1b}, {X0b, X1b}};

    for (int l = 0; l < 2; ++l) {
        const ushort* FA0T = FT + (size_t)(l * 5 + 0) * 16384;
        const ushort* FA1T = FT + (size_t)(l * 5 + 1) * 16384;
        const ushort* FA2T = FT + (size_t)(l * 5 + 2) * 16384;
        const ushort* FB1T = FT + (size_t)(l * 5 + 3) * 16384;
        const ushort* FB0T = FT + (size_t)(l * 5 + 4) * 16384;
        const float* fcH1 = FC + (l * 2 + 0) * 128;
        const float* fcH0 = FC + (l * 2 + 1) * 128;

        agg3<<<dim3(ag, 3), 256, 0, stream>>>(srcS[l][0], srcS[l][1], srcS[l][2],
                                              (uint*)Pb, (uint*)Rb, (uint*)Sb,
                                              offs, srcs, N, E);

        // y=0: Cq = Pb@FA0 + x1@FB1 ; y=1: Cp = Rb@FA1 + Sb@FA2 + x0@FB0
        gemm2_mfma<<<dim3(gg, 2), 256, 0, stream>>>(
            Pb, FA0T, dstX[l][1], FB1T,
            Rb, FA1T, Sb, FA2T, dstX[l][0], FB0T,
            fcH1, fcH0, Cq, Cp, N, ST + 256, ST);

        bn_fin2<<<1, 256, 0, stream>>>(ST, gam[l], bet[l], gam[l] + 128, bet[l] + 128, N);
        bn_apply2<<<dim3(1024, 2), 256, 0, stream>>>(Cp, X0b, Cq, X1b, ST, N * 32);
    }

    proj2<<<dim3(pg, 2), 256, 0, stream>>>((const uint*)X0b, (const uint*)X1b, Wp, bp, out, N);
}